// Round 1
// baseline (507.509 us; speedup 1.0000x reference)
//
#include <hip/hip_runtime.h>
#include <hip/hip_bf16.h>
#include <stdint.h>

typedef __attribute__((ext_vector_type(8))) short short8;
typedef __attribute__((ext_vector_type(4))) float f32x4;

__device__ inline unsigned short f2bf(float f) {
    union { float f; unsigned u; } v; v.f = f;
    unsigned u = v.u;
    unsigned r = u + 0x7fffu + ((u >> 16) & 1u);
    return (unsigned short)(r >> 16);
}

__device__ inline void gload_lds16(const void* g, void* l) {
    __builtin_amdgcn_global_load_lds((const __attribute__((address_space(1))) void*)g,
                                     (__attribute__((address_space(3))) void*)l,
                                     16, 0, 0);
}

// ---------------- cast x f32 -> bf16, 8 elems/thread ----------------
__global__ __launch_bounds__(256) void cast_x_kernel(const float* __restrict__ in,
                                                     unsigned short* __restrict__ out,
                                                     int n8) {
    int i = blockIdx.x * blockDim.x + threadIdx.x;
    int stride = gridDim.x * blockDim.x;
    for (; i < n8; i += stride) {
        const float4* p = (const float4*)(in + (size_t)i * 8);
        float4 a = p[0];
        float4 b = p[1];
        uint4 w;
        w.x = (unsigned)f2bf(a.x) | ((unsigned)f2bf(a.y) << 16);
        w.y = (unsigned)f2bf(a.z) | ((unsigned)f2bf(a.w) << 16);
        w.z = (unsigned)f2bf(b.x) | ((unsigned)f2bf(b.y) << 16);
        w.w = (unsigned)f2bf(b.z) | ((unsigned)f2bf(b.w) << 16);
        *(uint4*)(out + (size_t)i * 8) = w;
    }
}

// ---------------- cast+transpose: in[R][Cn] f32 -> out[Cn][R] bf16 ----------------
__global__ __launch_bounds__(256) void transpose_cast_kernel(const float* __restrict__ in,
                                                             unsigned short* __restrict__ out,
                                                             int R, int Cn) {
    __shared__ float tile[64][65];
    int t = threadIdx.x;
    int c0 = blockIdx.x * 64;
    int r0 = blockIdx.y * 64;
    int lr = t >> 4;
    int lc = (t & 15) * 4;
#pragma unroll
    for (int i = 0; i < 4; i++) {
        const float* src = in + (size_t)(r0 + i * 16 + lr) * Cn + c0 + lc;
        float4 v = *(const float4*)src;
        tile[i * 16 + lr][lc + 0] = v.x;
        tile[i * 16 + lr][lc + 1] = v.y;
        tile[i * 16 + lr][lc + 2] = v.z;
        tile[i * 16 + lr][lc + 3] = v.w;
    }
    __syncthreads();
    int oc = t >> 4;
    int ok = (t & 15) * 4;
#pragma unroll
    for (int i = 0; i < 4; i++) {
        int c = c0 + i * 16 + oc;
        ushort4 w;
        w.x = f2bf(tile[ok + 0][i * 16 + oc]);
        w.y = f2bf(tile[ok + 1][i * 16 + oc]);
        w.z = f2bf(tile[ok + 2][i * 16 + oc]);
        w.w = f2bf(tile[ok + 3][i * 16 + oc]);
        *(ushort4*)(out + (size_t)c * R + r0 + ok) = w;
    }
}

// ---------------- m97-structure GEMM: C[M][N] = A[M][K] * Bt[N][K]^T ----------------
// 128x128 tile, BK=32, 4 waves, each wave owns a 64x64 quadrant (4x4 16x16 frags).
template <int F32OUT>
__global__ __launch_bounds__(256) void gemm_bt(const unsigned short* __restrict__ A,
                                               const unsigned short* __restrict__ Bt,
                                               void* __restrict__ Cc,
                                               const float* __restrict__ bias,
                                               int M, int N, int K) {
    __shared__ unsigned short Alds[128 * 32];
    __shared__ unsigned short Blds[128 * 32];
    const int t = threadIdx.x;
    const int wave = t >> 6;
    const int lane = t & 63;
    const int brow = blockIdx.x;
    const int bcol = blockIdx.y;

    // staging: wave w covers rows [w*32, w*32+32) of each 128xBK tile, 16B/lane
    const int srow = wave * 32 + (lane >> 2);
    const int scol = (lane & 3) * 8;  // elements
    const unsigned short* gA = A + (size_t)(brow * 128 + srow) * K + scol;
    const unsigned short* gB = Bt + (size_t)(bcol * 128 + srow) * K + scol;
    char* lA = (char*)Alds + wave * 2048;
    char* lB = (char*)Blds + wave * 2048;

    const int wr = wave >> 1;
    const int wc = wave & 1;
    const unsigned short* aFrag = Alds + (wr * 64 + (lane & 15)) * 32 + (lane >> 4) * 8;
    const unsigned short* bFrag = Blds + (wc * 64 + (lane & 15)) * 32 + (lane >> 4) * 8;

    f32x4 acc[4][4] = {};

    for (int k0 = 0; k0 < K; k0 += 32) {
        __syncthreads();
        gload_lds16(gA + k0, lA);
        gload_lds16(gA + k0 + 16 * K, lA + 1024);
        gload_lds16(gB + k0, lB);
        gload_lds16(gB + k0 + 16 * K, lB + 1024);
        __syncthreads();
        short8 af[4], bf[4];
#pragma unroll
        for (int i = 0; i < 4; i++) af[i] = *(const short8*)(aFrag + i * 16 * 32);
#pragma unroll
        for (int i = 0; i < 4; i++) bf[i] = *(const short8*)(bFrag + i * 16 * 32);
#pragma unroll
        for (int mi = 0; mi < 4; mi++)
#pragma unroll
            for (int ni = 0; ni < 4; ni++)
                acc[mi][ni] = __builtin_amdgcn_mfma_f32_16x16x32_bf16(af[mi], bf[ni], acc[mi][ni], 0, 0, 0);
    }

    const int col0 = bcol * 128 + wc * 64;
    const int row0 = brow * 128 + wr * 64;
#pragma unroll
    for (int mi = 0; mi < 4; mi++) {
#pragma unroll
        for (int ni = 0; ni < 4; ni++) {
            int col = col0 + ni * 16 + (lane & 15);
            int rowb = row0 + mi * 16 + (lane >> 4) * 4;
            f32x4 v = acc[mi][ni];
            if constexpr (F32OUT) {
                float bz = bias[col];
                float* C = (float*)Cc;
#pragma unroll
                for (int q = 0; q < 4; q++)
                    C[(size_t)(rowb + q) * N + col] = v[q] + bz;
            } else {
                unsigned short* C = (unsigned short*)Cc;
#pragma unroll
                for (int q = 0; q < 4; q++)
                    C[(size_t)(rowb + q) * N + col] = f2bf(v[q]);
            }
        }
    }
}

// ---------------- per-token head-mixing attention ----------------
// one wave per token; qkv row = [q(16x64) | k(16x64) | v(16x64)] bf16.
// writes operm[b][h*256 + n/16][(n%16)*64 + d]  (fuses transpose+reshape)
__global__ __launch_bounds__(256) void attn_kernel(const unsigned short* __restrict__ qkv,
                                                   unsigned short* __restrict__ operm) {
    __shared__ __align__(16) float plds[4][16 * 20];
    const int wave = threadIdx.x >> 6;
    const int lane = threadIdx.x & 63;
    float* P = plds[wave];
    const int fr = lane & 15;
    const int fo = (lane >> 4) * 8;
    int tok = (blockIdx.x * 4 + wave) * 4;
    for (int it = 0; it < 4; it++, tok++) {
        const unsigned short* row = qkv + (size_t)tok * 3072;
        short8 aq0 = *(const short8*)(row + fr * 64 + fo);
        short8 aq1 = *(const short8*)(row + fr * 64 + 32 + fo);
        short8 bk0 = *(const short8*)(row + 1024 + fr * 64 + fo);
        short8 bk1 = *(const short8*)(row + 1024 + fr * 64 + 32 + fo);
        f32x4 s = {0.f, 0.f, 0.f, 0.f};
        s = __builtin_amdgcn_mfma_f32_16x16x32_bf16(aq0, bk0, s, 0, 0, 0);
        s = __builtin_amdgcn_mfma_f32_16x16x32_bf16(aq1, bk1, s, 0, 0, 0);
        // lane holds s[h][g]: h=(lane>>4)*4+q, g=lane&15. softmax over g (16-lane groups)
        float ls[4], m[4], p[4], sm[4];
#pragma unroll
        for (int q = 0; q < 4; q++) { ls[q] = s[q] * 0.125f; m[q] = ls[q]; }
#pragma unroll
        for (int d = 1; d < 16; d <<= 1)
#pragma unroll
            for (int q = 0; q < 4; q++) m[q] = fmaxf(m[q], __shfl_xor(m[q], d));
#pragma unroll
        for (int q = 0; q < 4; q++) { p[q] = __expf(ls[q] - m[q]); sm[q] = p[q]; }
#pragma unroll
        for (int d = 1; d < 16; d <<= 1)
#pragma unroll
            for (int q = 0; q < 4; q++) sm[q] += __shfl_xor(sm[q], d);
        // stash unnormalized P[h][g] to LDS, re-read in MFMA A-frag layout
#pragma unroll
        for (int q = 0; q < 4; q++) P[((lane >> 4) * 4 + q) * 20 + fr] = p[q];
        __syncthreads();
        short8 pa = {};
        if (lane < 32) {
            const float* src = P + fr * 20 + fo;  // P[h=fr][g=fo..fo+7]
            float4 r0 = *(const float4*)src;
            float4 r1 = *(const float4*)(src + 4);
            pa[0] = (short)f2bf(r0.x); pa[1] = (short)f2bf(r0.y);
            pa[2] = (short)f2bf(r0.z); pa[3] = (short)f2bf(r0.w);
            pa[4] = (short)f2bf(r1.x); pa[5] = (short)f2bf(r1.y);
            pa[6] = (short)f2bf(r1.z); pa[7] = (short)f2bf(r1.w);
        }
        __syncthreads();
        // PV: O[h][d] = sum_g P[h][g] V[g][d], K padded 16->32 (A zero in upper half)
        f32x4 o[4] = {};
        const unsigned short* vrow = row + 2048;
#pragma unroll
        for (int db = 0; db < 4; db++) {
            short8 bv = {};
            if (lane < 32) {
#pragma unroll
                for (int j = 0; j < 8; j++)
                    bv[j] = (short)vrow[(fo + j) * 64 + db * 16 + fr];
            }
            o[db] = __builtin_amdgcn_mfma_f32_16x16x32_bf16(pa, bv, o[db], 0, 0, 0);
        }
        float inv[4];
#pragma unroll
        for (int q = 0; q < 4; q++) inv[q] = 1.0f / sm[q];
        int b = tok >> 12;
        int n = tok & 4095;
        unsigned short* obase = operm + ((size_t)b << 22);
        int rlo = n >> 4;
        int cbase = (n & 15) * 64;
#pragma unroll
        for (int db = 0; db < 4; db++) {
#pragma unroll
            for (int q = 0; q < 4; q++) {
                int h = (lane >> 4) * 4 + q;
                int d = db * 16 + fr;
                obase[(size_t)(h * 256 + rlo) * 1024 + cbase + d] = f2bf(o[db][q] * inv[q]);
            }
        }
    }
}

extern "C" void kernel_launch(void* const* d_in, const int* in_sizes, int n_in,
                              void* d_out, int out_size, void* d_ws, size_t ws_size,
                              hipStream_t stream) {
    const float* x = (const float*)d_in[0];
    const float* w_qkv = (const float*)d_in[1];
    const float* w_proj = (const float*)d_in[2];
    const float* b_proj = (const float*)d_in[3];
    float* out = (float*)d_out;

    char* ws = (char*)d_ws;
    unsigned short* x_bf  = (unsigned short*)(ws);                  //  64 MiB: [32768][1024]
    unsigned short* wq_t  = (unsigned short*)(ws + 67108864);       //   6 MiB: [3072][1024]
    unsigned short* wp_t  = (unsigned short*)(ws + 73400320);       //   2 MiB: [1024][1024]
    unsigned short* qkv   = (unsigned short*)(ws + 75497472);       // 192 MiB: [32768][3072]
    unsigned short* operm = (unsigned short*)(ws + 276824064);      //  64 MiB: [32768][1024]

    cast_x_kernel<<<2048, 256, 0, stream>>>(x, x_bf, 33554432 / 8);
    transpose_cast_kernel<<<dim3(48, 16), 256, 0, stream>>>(w_qkv, wq_t, 1024, 3072);
    transpose_cast_kernel<<<dim3(16, 16), 256, 0, stream>>>(w_proj, wp_t, 1024, 1024);
    gemm_bt<0><<<dim3(256, 24), 256, 0, stream>>>(x_bf, wq_t, qkv, nullptr, 32768, 3072, 1024);
    attn_kernel<<<2048, 256, 0, stream>>>(qkv, operm);
    gemm_bt<1><<<dim3(256, 8), 256, 0, stream>>>(operm, wp_t, out, b_proj, 32768, 1024, 1024);
}

// Round 2
// 421.532 us; speedup vs baseline: 1.2040x; 1.2040x over previous
//
#include <hip/hip_runtime.h>
#include <hip/hip_bf16.h>
#include <stdint.h>

typedef __attribute__((ext_vector_type(8))) short short8;
typedef __attribute__((ext_vector_type(4))) float f32x4;
typedef unsigned short ushort_t;

#define VMCNT4 asm volatile("s_waitcnt vmcnt(4)" ::: "memory")
#define VMCNT0 asm volatile("s_waitcnt vmcnt(0)" ::: "memory")
#define LGKM0  asm volatile("s_waitcnt lgkmcnt(0)" ::: "memory")
#define BARRIER asm volatile("s_barrier" ::: "memory")

__device__ inline ushort_t f2bf(float f) {
    union { float f; unsigned u; } v; v.f = f;
    unsigned u = v.u;
    unsigned r = u + 0x7fffu + ((u >> 16) & 1u);
    return (ushort_t)(r >> 16);
}

__device__ inline void gload_lds16(const void* g, void* l) {
    __builtin_amdgcn_global_load_lds((const __attribute__((address_space(1))) void*)g,
                                     (__attribute__((address_space(3))) void*)l,
                                     16, 0, 0);
}

// swizzled LDS frag read: region = 128x64 bf16 row-major (128B rows), st_16x32 XOR
__device__ inline short8 read_frag(const ushort_t* region, int r, int c) {
    int byte = (r << 7) + (c << 1);
    byte ^= ((byte >> 9) & 1) << 5;
    return *(const short8*)((const char*)region + byte);
}

#define MFMA16(MB, NB, BF)                                                        \
    _Pragma("unroll")                                                             \
    for (int mi = 0; mi < 4; ++mi)                                                \
        _Pragma("unroll")                                                         \
        for (int ni = 0; ni < 2; ++ni)                                            \
            _Pragma("unroll")                                                     \
            for (int ks = 0; ks < 2; ++ks)                                        \
                acc[(MB) + mi][(NB) + ni] = __builtin_amdgcn_mfma_f32_16x16x32_bf16( \
                    aF[mi * 2 + ks], BF[ni * 2 + ks], acc[(MB) + mi][(NB) + ni], 0, 0, 0);

// ---------------- 256x256 8-phase GEMM: C[M][N] = A[M][K] * Bt[N][K]^T ----------------
// 8 waves (2M x 4N), BK=64, 128 KiB LDS (2 slots x 2 halves x 128x64 per operand),
// st_16x32 swizzle (linear gload_lds dest + pre-swizzled source + swizzled ds_read),
// counted vmcnt(4) checkpoint once per K-tile.  [8-phase template, m201 lineage]
template <int F32OUT>
__global__ __launch_bounds__(512, 2) void gemm256(const ushort_t* __restrict__ A,
                                                  const ushort_t* __restrict__ Bt,
                                                  void* __restrict__ Cc,
                                                  const float* __restrict__ bias,
                                                  int N, int K, int NBN) {
    __shared__ __align__(16) ushort_t lds[65536];  // 128 KiB
    const int tid = threadIdx.x;
    const int wave = tid >> 6;
    const int lane = tid & 63;
    const int wm = wave >> 2;   // 0..1
    const int wn = wave & 3;    // 0..3
    // pre-swizzled source lane: lanes >=32 swap pairs (inverse of byte-bit5^bit9 XOR)
    const int el = lane ^ (((lane >> 5) & 1) << 1);

    // XCD-bijective swizzle (nwg%8==0) + 8-row supertile rasterization
    const int nwg = gridDim.x;
    const int bid = (int)blockIdx.x;
    const int x = (bid & 7) * (nwg >> 3) + (bid >> 3);
    const int per = NBN << 3;
    const int st = x / per;
    const int rem = x - st * per;
    const int bn = rem >> 3;
    const int bm = (st << 3) + (rem & 7);

    const ushort_t* Ag = A + (size_t)bm * 256 * K;
    const ushort_t* Bg = Bt + (size_t)bn * 256 * K;
    const int NT = K >> 6;

    auto STAGE = [&](const ushort_t* g, int rowHalf, int k0, int regionByteOff) {
#pragma unroll
        for (int j = 0; j < 2; ++j) {
            int e = j * 4096 + wave * 512 + el * 8;  // element within 128x64 half
            gload_lds16(g + (size_t)(rowHalf + (e >> 6)) * K + k0 + (e & 63),
                        (char*)lds + regionByteOff + j * 8192 + wave * 1024);
        }
    };

    // regions (bytes): A(slot,h) = (slot*2+h)*16384 ; B(slot,h) = 65536 + (slot*2+h)*16384
    // prologue: tile0 -> slot0 (all 4 halves), tile1 B-halves -> slot1
    STAGE(Ag, 0,   0, 0);
    STAGE(Ag, 128, 0, 16384);
    STAGE(Bg, 0,   0, 65536);
    STAGE(Bg, 128, 0, 65536 + 16384);
    STAGE(Bg, 0,   64, 65536 + 32768);
    STAGE(Bg, 128, 64, 65536 + 49152);
    VMCNT4;   // tile0 complete; tile1 B-halves stay in flight
    BARRIER;

    f32x4 acc[8][4] = {};
    short8 aF[8], bF0[4], bF1[4];
    const int ra = lane & 15;
    const int ca = (lane >> 4) << 3;
    const int rb = (wn & 1) << 6;

    for (int it = 0; it < NT; ++it) {
        const int s = it & 1;
        const ushort_t* Ar = lds + ((s << 1) + wm) * 8192;
        const ushort_t* Br = lds + 32768 + ((s << 1) + (wn >> 1)) * 8192;
        const bool doA = (it + 1) < NT;
        const bool doB = (it + 2) < NT;
        const int kA = (it + 1) << 6;
        const int kB = (it + 2) << 6;
        const int soA = ((s ^ 1) << 1) * 16384;        // other-slot A base
        const int soB = 65536 + (s << 1) * 16384;      // own-slot B base

        // ---- phase 1: read aF(m-half0) + bF0 ; stage (s^1).A0 <- tile it+1
#pragma unroll
        for (int mi = 0; mi < 4; ++mi)
#pragma unroll
            for (int ks = 0; ks < 2; ++ks)
                aF[mi * 2 + ks] = read_frag(Ar, mi * 16 + ra, ks * 32 + ca);
#pragma unroll
        for (int ni = 0; ni < 2; ++ni)
#pragma unroll
            for (int ks = 0; ks < 2; ++ks)
                bF0[ni * 2 + ks] = read_frag(Br, rb + ni * 16 + ra, ks * 32 + ca);
        if (doA) STAGE(Ag, 0, kA, soA);
        BARRIER; LGKM0;
        __builtin_amdgcn_s_setprio(1);
        MFMA16(0, 0, bF0)
        __builtin_amdgcn_s_setprio(0);
        BARRIER;

        // ---- phase 2: read bF1 ; stage (s^1).A1
#pragma unroll
        for (int ni = 0; ni < 2; ++ni)
#pragma unroll
            for (int ks = 0; ks < 2; ++ks)
                bF1[ni * 2 + ks] = read_frag(Br, rb + 32 + ni * 16 + ra, ks * 32 + ca);
        if (doA) STAGE(Ag, 128, kA, soA + 16384);
        BARRIER; LGKM0;
        __builtin_amdgcn_s_setprio(1);
        MFMA16(0, 2, bF1)
        __builtin_amdgcn_s_setprio(0);
        BARRIER;

        // ---- phase 3: read aF(m-half1) ; stage s.B0 <- tile it+2
#pragma unroll
        for (int mi = 0; mi < 4; ++mi)
#pragma unroll
            for (int ks = 0; ks < 2; ++ks)
                aF[mi * 2 + ks] = read_frag(Ar, 64 + mi * 16 + ra, ks * 32 + ca);
        if (doB) STAGE(Bg, 0, kB, soB);
        BARRIER; LGKM0;
        __builtin_amdgcn_s_setprio(1);
        MFMA16(4, 0, bF0)
        __builtin_amdgcn_s_setprio(0);
        BARRIER;

        // ---- phase 4: stage s.B1 ; vmcnt checkpoint ; compute (m1,n-hi)
        if (doB) STAGE(Bg, 128, kB, soB + 16384);
        if (doB) { VMCNT4; } else { VMCNT0; }
        BARRIER; LGKM0;
        __builtin_amdgcn_s_setprio(1);
        MFMA16(4, 2, bF1)
        __builtin_amdgcn_s_setprio(0);
        BARRIER;
    }

    // epilogue
    const int row0 = bm * 256 + wm * 128 + (lane >> 4) * 4;
    const int col0 = bn * 256 + wn * 64 + (lane & 15);
#pragma unroll
    for (int mi = 0; mi < 8; ++mi) {
#pragma unroll
        for (int ni = 0; ni < 4; ++ni) {
            const int col = col0 + ni * 16;
            f32x4 v = acc[mi][ni];
            if constexpr (F32OUT) {
                float bz = bias[col];
                float* C = (float*)Cc;
#pragma unroll
                for (int q = 0; q < 4; ++q)
                    C[(size_t)(row0 + mi * 16 + q) * N + col] = v[q] + bz;
            } else {
                ushort_t* C = (ushort_t*)Cc;
#pragma unroll
                for (int q = 0; q < 4; ++q)
                    C[(size_t)(row0 + mi * 16 + q) * N + col] = f2bf(v[q]);
            }
        }
    }
}

// ---------------- cast x f32 -> bf16, 8 elems/thread ----------------
__global__ __launch_bounds__(256) void cast_x_kernel(const float* __restrict__ in,
                                                     ushort_t* __restrict__ out,
                                                     int n8) {
    int i = blockIdx.x * blockDim.x + threadIdx.x;
    int stride = gridDim.x * blockDim.x;
    for (; i < n8; i += stride) {
        const float4* p = (const float4*)(in + (size_t)i * 8);
        float4 a = p[0];
        float4 b = p[1];
        uint4 w;
        w.x = (unsigned)f2bf(a.x) | ((unsigned)f2bf(a.y) << 16);
        w.y = (unsigned)f2bf(a.z) | ((unsigned)f2bf(a.w) << 16);
        w.z = (unsigned)f2bf(b.x) | ((unsigned)f2bf(b.y) << 16);
        w.w = (unsigned)f2bf(b.z) | ((unsigned)f2bf(b.w) << 16);
        *(uint4*)(out + (size_t)i * 8) = w;
    }
}

// ---------------- cast+transpose: in[R][Cn] f32 -> out[Cn][R] bf16 ----------------
__global__ __launch_bounds__(256) void transpose_cast_kernel(const float* __restrict__ in,
                                                             ushort_t* __restrict__ out,
                                                             int R, int Cn) {
    __shared__ float tile[64][65];
    int t = threadIdx.x;
    int c0 = blockIdx.x * 64;
    int r0 = blockIdx.y * 64;
    int lr = t >> 4;
    int lc = (t & 15) * 4;
#pragma unroll
    for (int i = 0; i < 4; i++) {
        const float* src = in + (size_t)(r0 + i * 16 + lr) * Cn + c0 + lc;
        float4 v = *(const float4*)src;
        tile[i * 16 + lr][lc + 0] = v.x;
        tile[i * 16 + lr][lc + 1] = v.y;
        tile[i * 16 + lr][lc + 2] = v.z;
        tile[i * 16 + lr][lc + 3] = v.w;
    }
    __syncthreads();
    int oc = t >> 4;
    int ok = (t & 15) * 4;
#pragma unroll
    for (int i = 0; i < 4; i++) {
        int c = c0 + i * 16 + oc;
        ushort4 w;
        w.x = f2bf(tile[ok + 0][i * 16 + oc]);
        w.y = f2bf(tile[ok + 1][i * 16 + oc]);
        w.z = f2bf(tile[ok + 2][i * 16 + oc]);
        w.w = f2bf(tile[ok + 3][i * 16 + oc]);
        *(ushort4*)(out + (size_t)c * R + r0 + ok) = w;
    }
}

// ---------------- per-token head-mixing attention ----------------
__global__ __launch_bounds__(256) void attn_kernel(const ushort_t* __restrict__ qkv,
                                                   ushort_t* __restrict__ operm) {
    __shared__ __align__(16) float plds[4][16 * 20];
    const int wave = threadIdx.x >> 6;
    const int lane = threadIdx.x & 63;
    float* P = plds[wave];
    const int fr = lane & 15;
    const int fo = (lane >> 4) * 8;
    int tok = (blockIdx.x * 4 + wave) * 4;
    for (int it = 0; it < 4; it++, tok++) {
        const ushort_t* row = qkv + (size_t)tok * 3072;
        short8 aq0 = *(const short8*)(row + fr * 64 + fo);
        short8 aq1 = *(const short8*)(row + fr * 64 + 32 + fo);
        short8 bk0 = *(const short8*)(row + 1024 + fr * 64 + fo);
        short8 bk1 = *(const short8*)(row + 1024 + fr * 64 + 32 + fo);
        f32x4 s = {0.f, 0.f, 0.f, 0.f};
        s = __builtin_amdgcn_mfma_f32_16x16x32_bf16(aq0, bk0, s, 0, 0, 0);
        s = __builtin_amdgcn_mfma_f32_16x16x32_bf16(aq1, bk1, s, 0, 0, 0);
        float ls[4], m[4], p[4], sm[4];
#pragma unroll
        for (int q = 0; q < 4; q++) { ls[q] = s[q] * 0.125f; m[q] = ls[q]; }
#pragma unroll
        for (int d = 1; d < 16; d <<= 1)
#pragma unroll
            for (int q = 0; q < 4; q++) m[q] = fmaxf(m[q], __shfl_xor(m[q], d));
#pragma unroll
        for (int q = 0; q < 4; q++) { p[q] = __expf(ls[q] - m[q]); sm[q] = p[q]; }
#pragma unroll
        for (int d = 1; d < 16; d <<= 1)
#pragma unroll
            for (int q = 0; q < 4; q++) sm[q] += __shfl_xor(sm[q], d);
#pragma unroll
        for (int q = 0; q < 4; q++) P[((lane >> 4) * 4 + q) * 20 + fr] = p[q];
        __syncthreads();
        short8 pa = {};
        if (lane < 32) {
            const float* src = P + fr * 20 + fo;
            float4 r0 = *(const float4*)src;
            float4 r1 = *(const float4*)(src + 4);
            pa[0] = (short)f2bf(r0.x); pa[1] = (short)f2bf(r0.y);
            pa[2] = (short)f2bf(r0.z); pa[3] = (short)f2bf(r0.w);
            pa[4] = (short)f2bf(r1.x); pa[5] = (short)f2bf(r1.y);
            pa[6] = (short)f2bf(r1.z); pa[7] = (short)f2bf(r1.w);
        }
        __syncthreads();
        f32x4 o[4] = {};
        const ushort_t* vrow = row + 2048;
#pragma unroll
        for (int db = 0; db < 4; db++) {
            short8 bv = {};
            if (lane < 32) {
#pragma unroll
                for (int j = 0; j < 8; j++)
                    bv[j] = (short)vrow[(fo + j) * 64 + db * 16 + fr];
            }
            o[db] = __builtin_amdgcn_mfma_f32_16x16x32_bf16(pa, bv, o[db], 0, 0, 0);
        }
        float inv[4];
#pragma unroll
        for (int q = 0; q < 4; q++) inv[q] = 1.0f / sm[q];
        int b = tok >> 12;
        int n = tok & 4095;
        ushort_t* obase = operm + ((size_t)b << 22);
        int rlo = n >> 4;
        int cbase = (n & 15) * 64;
#pragma unroll
        for (int db = 0; db < 4; db++) {
#pragma unroll
            for (int q = 0; q < 4; q++) {
                int h = (lane >> 4) * 4 + q;
                int d = db * 16 + fr;
                obase[(size_t)(h * 256 + rlo) * 1024 + cbase + d] = f2bf(o[db][q] * inv[q]);
            }
        }
    }
}

extern "C" void kernel_launch(void* const* d_in, const int* in_sizes, int n_in,
                              void* d_out, int out_size, void* d_ws, size_t ws_size,
                              hipStream_t stream) {
    const float* x = (const float*)d_in[0];
    const float* w_qkv = (const float*)d_in[1];
    const float* w_proj = (const float*)d_in[2];
    const float* b_proj = (const float*)d_in[3];
    float* out = (float*)d_out;

    char* ws = (char*)d_ws;
    ushort_t* x_bf  = (ushort_t*)(ws);                  //  64 MiB: [32768][1024]
    ushort_t* wq_t  = (ushort_t*)(ws + 67108864);       //   6 MiB: [3072][1024]
    ushort_t* wp_t  = (ushort_t*)(ws + 73400320);       //   2 MiB: [1024][1024]
    ushort_t* qkv   = (ushort_t*)(ws + 75497472);       // 192 MiB: [32768][3072]
    ushort_t* operm = (ushort_t*)(ws + 276824064);      //  64 MiB: [32768][1024]

    cast_x_kernel<<<2048, 256, 0, stream>>>(x, x_bf, 33554432 / 8);
    transpose_cast_kernel<<<dim3(48, 16), 256, 0, stream>>>(w_qkv, wq_t, 1024, 3072);
    transpose_cast_kernel<<<dim3(16, 16), 256, 0, stream>>>(w_proj, wp_t, 1024, 1024);
    gemm256<0><<<1536, 512, 0, stream>>>(x_bf, wq_t, qkv, nullptr, 3072, 1024, 12);
    attn_kernel<<<2048, 256, 0, stream>>>(qkv, operm);
    gemm256<1><<<512, 512, 0, stream>>>(operm, wp_t, out, b_proj, 1024, 1024, 4);
}

// Round 3
// 399.144 us; speedup vs baseline: 1.2715x; 1.0561x over previous
//
#include <hip/hip_runtime.h>
#include <hip/hip_bf16.h>
#include <stdint.h>

typedef __attribute__((ext_vector_type(8))) short short8;
typedef __attribute__((ext_vector_type(4))) float f32x4;
typedef unsigned short ushort_t;

#define VMCNT4 asm volatile("s_waitcnt vmcnt(4)" ::: "memory")
#define VMCNT0 asm volatile("s_waitcnt vmcnt(0)" ::: "memory")
#define LGKM0  asm volatile("s_waitcnt lgkmcnt(0)" ::: "memory")
#define BARRIER asm volatile("s_barrier" ::: "memory")

__device__ inline ushort_t f2bf(float f) {
    union { float f; unsigned u; } v; v.f = f;
    unsigned u = v.u;
    unsigned r = u + 0x7fffu + ((u >> 16) & 1u);
    return (ushort_t)(r >> 16);
}

__device__ inline void gload_lds16(const void* g, void* l) {
    __builtin_amdgcn_global_load_lds((const __attribute__((address_space(1))) void*)g,
                                     (__attribute__((address_space(3))) void*)l,
                                     16, 0, 0);
}

// swizzled LDS frag read: region = 128x64 bf16 row-major (128B rows).
// Guideline-4 swizzle: XOR low 3 row bits into the 16B-slot index (byte bits 4-6).
// 16 lanes at row-stride 128B now spread across all 8 slots -> minimum-beat b128 reads.
__device__ inline short8 read_frag(const ushort_t* region, int r, int c) {
    int byte = (r << 7) + (c << 1);
    byte ^= (r & 7) << 4;
    return *(const short8*)((const char*)region + byte);
}

#define MFMA16(MB, NB, BF)                                                        \
    _Pragma("unroll")                                                             \
    for (int mi = 0; mi < 4; ++mi)                                                \
        _Pragma("unroll")                                                         \
        for (int ni = 0; ni < 2; ++ni)                                            \
            _Pragma("unroll")                                                     \
            for (int ks = 0; ks < 2; ++ks)                                        \
                acc[(MB) + mi][(NB) + ni] = __builtin_amdgcn_mfma_f32_16x16x32_bf16( \
                    aF[mi * 2 + ks], BF[ni * 2 + ks], acc[(MB) + mi][(NB) + ni], 0, 0, 0);

// ---------------- 256x256 8-phase GEMM: C[M][N] = A[M][K] * Bt[N][K]^T ----------------
// 8 waves (2M x 4N), BK=64, 128 KiB LDS (2 slots x 2 halves x 128x64 per operand),
// row&7 XOR swizzle (linear gload_lds dest + pre-swizzled source + swizzled ds_read),
// counted vmcnt(4) checkpoint once per K-tile.  [8-phase template, m201 lineage]
template <int F32OUT>
__global__ __launch_bounds__(512, 2) void gemm256(const ushort_t* __restrict__ A,
                                                  const ushort_t* __restrict__ Bt,
                                                  void* __restrict__ Cc,
                                                  const float* __restrict__ bias,
                                                  int N, int K, int NBN) {
    __shared__ __align__(16) ushort_t lds[65536];  // 128 KiB
    const int tid = threadIdx.x;
    const int wave = tid >> 6;
    const int lane = tid & 63;
    const int wm = wave >> 2;   // 0..1
    const int wn = wave & 3;    // 0..3
    // pre-swizzled source lane: linear LDS slot = lane&7, row-within-stripe = lane>>3;
    // fetch global column (slot ^ row)*8 so lds[swz(addr)] = logical[addr]
    const int el = (lane & 56) | ((lane ^ (lane >> 3)) & 7);

    // XCD-bijective swizzle (nwg%8==0) + 8-row supertile rasterization
    const int nwg = gridDim.x;
    const int bid = (int)blockIdx.x;
    const int x = (bid & 7) * (nwg >> 3) + (bid >> 3);
    const int per = NBN << 3;
    const int st = x / per;
    const int rem = x - st * per;
    const int bn = rem >> 3;
    const int bm = (st << 3) + (rem & 7);

    const ushort_t* Ag = A + (size_t)bm * 256 * K;
    const ushort_t* Bg = Bt + (size_t)bn * 256 * K;
    const int NT = K >> 6;

    auto STAGE = [&](const ushort_t* g, int rowHalf, int k0, int regionByteOff) {
#pragma unroll
        for (int j = 0; j < 2; ++j) {
            int e = j * 4096 + wave * 512 + el * 8;  // element within 128x64 half
            gload_lds16(g + (size_t)(rowHalf + (e >> 6)) * K + k0 + (e & 63),
                        (char*)lds + regionByteOff + j * 8192 + wave * 1024);
        }
    };

    // regions (bytes): A(slot,h) = (slot*2+h)*16384 ; B(slot,h) = 65536 + (slot*2+h)*16384
    // prologue: tile0 -> slot0 (all 4 halves), tile1 B-halves -> slot1
    STAGE(Ag, 0,   0, 0);
    STAGE(Ag, 128, 0, 16384);
    STAGE(Bg, 0,   0, 65536);
    STAGE(Bg, 128, 0, 65536 + 16384);
    STAGE(Bg, 0,   64, 65536 + 32768);
    STAGE(Bg, 128, 64, 65536 + 49152);
    VMCNT4;   // tile0 complete; tile1 B-halves stay in flight
    BARRIER;

    f32x4 acc[8][4] = {};
    short8 aF[8], bF0[4], bF1[4];
    const int ra = lane & 15;
    const int ca = (lane >> 4) << 3;
    const int rb = (wn & 1) << 6;

    for (int it = 0; it < NT; ++it) {
        const int s = it & 1;
        const ushort_t* Ar = lds + ((s << 1) + wm) * 8192;
        const ushort_t* Br = lds + 32768 + ((s << 1) + (wn >> 1)) * 8192;
        const bool doA = (it + 1) < NT;
        const bool doB = (it + 2) < NT;
        const int kA = (it + 1) << 6;
        const int kB = (it + 2) << 6;
        const int soA = ((s ^ 1) << 1) * 16384;        // other-slot A base
        const int soB = 65536 + (s << 1) * 16384;      // own-slot B base

        // ---- phase 1: read aF(m-half0) + bF0 ; stage (s^1).A0 <- tile it+1
#pragma unroll
        for (int mi = 0; mi < 4; ++mi)
#pragma unroll
            for (int ks = 0; ks < 2; ++ks)
                aF[mi * 2 + ks] = read_frag(Ar, mi * 16 + ra, ks * 32 + ca);
#pragma unroll
        for (int ni = 0; ni < 2; ++ni)
#pragma unroll
            for (int ks = 0; ks < 2; ++ks)
                bF0[ni * 2 + ks] = read_frag(Br, rb + ni * 16 + ra, ks * 32 + ca);
        if (doA) STAGE(Ag, 0, kA, soA);
        BARRIER; LGKM0;
        __builtin_amdgcn_s_setprio(1);
        MFMA16(0, 0, bF0)
        __builtin_amdgcn_s_setprio(0);
        BARRIER;

        // ---- phase 2: read bF1 ; stage (s^1).A1
#pragma unroll
        for (int ni = 0; ni < 2; ++ni)
#pragma unroll
            for (int ks = 0; ks < 2; ++ks)
                bF1[ni * 2 + ks] = read_frag(Br, rb + 32 + ni * 16 + ra, ks * 32 + ca);
        if (doA) STAGE(Ag, 128, kA, soA + 16384);
        BARRIER; LGKM0;
        __builtin_amdgcn_s_setprio(1);
        MFMA16(0, 2, bF1)
        __builtin_amdgcn_s_setprio(0);
        BARRIER;

        // ---- phase 3: read aF(m-half1) ; stage s.B0 <- tile it+2
#pragma unroll
        for (int mi = 0; mi < 4; ++mi)
#pragma unroll
            for (int ks = 0; ks < 2; ++ks)
                aF[mi * 2 + ks] = read_frag(Ar, 64 + mi * 16 + ra, ks * 32 + ca);
        if (doB) STAGE(Bg, 0, kB, soB);
        BARRIER; LGKM0;
        __builtin_amdgcn_s_setprio(1);
        MFMA16(4, 0, bF0)
        __builtin_amdgcn_s_setprio(0);
        BARRIER;

        // ---- phase 4: stage s.B1 ; vmcnt checkpoint ; compute (m1,n-hi)
        if (doB) STAGE(Bg, 128, kB, soB + 16384);
        if (doB) { VMCNT4; } else { VMCNT0; }
        BARRIER; LGKM0;
        __builtin_amdgcn_s_setprio(1);
        MFMA16(4, 2, bF1)
        __builtin_amdgcn_s_setprio(0);
        BARRIER;
    }

    // epilogue
    const int row0 = bm * 256 + wm * 128 + (lane >> 4) * 4;
    const int col0 = bn * 256 + wn * 64 + (lane & 15);
#pragma unroll
    for (int mi = 0; mi < 8; ++mi) {
#pragma unroll
        for (int ni = 0; ni < 4; ++ni) {
            const int col = col0 + ni * 16;
            f32x4 v = acc[mi][ni];
            if constexpr (F32OUT) {
                float bz = bias[col];
                float* C = (float*)Cc;
#pragma unroll
                for (int q = 0; q < 4; ++q)
                    C[(size_t)(row0 + mi * 16 + q) * N + col] = v[q] + bz;
            } else {
                ushort_t* C = (ushort_t*)Cc;
#pragma unroll
                for (int q = 0; q < 4; ++q)
                    C[(size_t)(row0 + mi * 16 + q) * N + col] = f2bf(v[q]);
            }
        }
    }
}

// ---------------- cast x f32 -> bf16, 8 elems/thread ----------------
__global__ __launch_bounds__(256) void cast_x_kernel(const float* __restrict__ in,
                                                     ushort_t* __restrict__ out,
                                                     int n8) {
    int i = blockIdx.x * blockDim.x + threadIdx.x;
    int stride = gridDim.x * blockDim.x;
    for (; i < n8; i += stride) {
        const float4* p = (const float4*)(in + (size_t)i * 8);
        float4 a = p[0];
        float4 b = p[1];
        uint4 w;
        w.x = (unsigned)f2bf(a.x) | ((unsigned)f2bf(a.y) << 16);
        w.y = (unsigned)f2bf(a.z) | ((unsigned)f2bf(a.w) << 16);
        w.z = (unsigned)f2bf(b.x) | ((unsigned)f2bf(b.y) << 16);
        w.w = (unsigned)f2bf(b.z) | ((unsigned)f2bf(b.w) << 16);
        *(uint4*)(out + (size_t)i * 8) = w;
    }
}

// ---------------- cast+transpose: in[R][Cn] f32 -> out[Cn][R] bf16 ----------------
__global__ __launch_bounds__(256) void transpose_cast_kernel(const float* __restrict__ in,
                                                             ushort_t* __restrict__ out,
                                                             int R, int Cn) {
    __shared__ float tile[64][65];
    int t = threadIdx.x;
    int c0 = blockIdx.x * 64;
    int r0 = blockIdx.y * 64;
    int lr = t >> 4;
    int lc = (t & 15) * 4;
#pragma unroll
    for (int i = 0; i < 4; i++) {
        const float* src = in + (size_t)(r0 + i * 16 + lr) * Cn + c0 + lc;
        float4 v = *(const float4*)src;
        tile[i * 16 + lr][lc + 0] = v.x;
        tile[i * 16 + lr][lc + 1] = v.y;
        tile[i * 16 + lr][lc + 2] = v.z;
        tile[i * 16 + lr][lc + 3] = v.w;
    }
    __syncthreads();
    int oc = t >> 4;
    int ok = (t & 15) * 4;
#pragma unroll
    for (int i = 0; i < 4; i++) {
        int c = c0 + i * 16 + oc;
        ushort4 w;
        w.x = f2bf(tile[ok + 0][i * 16 + oc]);
        w.y = f2bf(tile[ok + 1][i * 16 + oc]);
        w.z = f2bf(tile[ok + 2][i * 16 + oc]);
        w.w = f2bf(tile[ok + 3][i * 16 + oc]);
        *(ushort4*)(out + (size_t)c * R + r0 + ok) = w;
    }
}

// ---------------- per-token head-mixing attention ----------------
__global__ __launch_bounds__(256) void attn_kernel(const ushort_t* __restrict__ qkv,
                                                   ushort_t* __restrict__ operm) {
    __shared__ __align__(16) float plds[4][16 * 20];
    const int wave = threadIdx.x >> 6;
    const int lane = threadIdx.x & 63;
    float* P = plds[wave];
    const int fr = lane & 15;
    const int fo = (lane >> 4) * 8;
    int tok = (blockIdx.x * 4 + wave) * 4;
    for (int it = 0; it < 4; it++, tok++) {
        const ushort_t* row = qkv + (size_t)tok * 3072;
        short8 aq0 = *(const short8*)(row + fr * 64 + fo);
        short8 aq1 = *(const short8*)(row + fr * 64 + 32 + fo);
        short8 bk0 = *(const short8*)(row + 1024 + fr * 64 + fo);
        short8 bk1 = *(const short8*)(row + 1024 + fr * 64 + 32 + fo);
        f32x4 s = {0.f, 0.f, 0.f, 0.f};
        s = __builtin_amdgcn_mfma_f32_16x16x32_bf16(aq0, bk0, s, 0, 0, 0);
        s = __builtin_amdgcn_mfma_f32_16x16x32_bf16(aq1, bk1, s, 0, 0, 0);
        float ls[4], m[4], p[4], sm[4];
#pragma unroll
        for (int q = 0; q < 4; q++) { ls[q] = s[q] * 0.125f; m[q] = ls[q]; }
#pragma unroll
        for (int d = 1; d < 16; d <<= 1)
#pragma unroll
            for (int q = 0; q < 4; q++) m[q] = fmaxf(m[q], __shfl_xor(m[q], d));
#pragma unroll
        for (int q = 0; q < 4; q++) { p[q] = __expf(ls[q] - m[q]); sm[q] = p[q]; }
#pragma unroll
        for (int d = 1; d < 16; d <<= 1)
#pragma unroll
            for (int q = 0; q < 4; q++) sm[q] += __shfl_xor(sm[q], d);
#pragma unroll
        for (int q = 0; q < 4; q++) P[((lane >> 4) * 4 + q) * 20 + fr] = p[q];
        __syncthreads();
        short8 pa = {};
        if (lane < 32) {
            const float* src = P + fr * 20 + fo;
            float4 r0 = *(const float4*)src;
            float4 r1 = *(const float4*)(src + 4);
            pa[0] = (short)f2bf(r0.x); pa[1] = (short)f2bf(r0.y);
            pa[2] = (short)f2bf(r0.z); pa[3] = (short)f2bf(r0.w);
            pa[4] = (short)f2bf(r1.x); pa[5] = (short)f2bf(r1.y);
            pa[6] = (short)f2bf(r1.z); pa[7] = (short)f2bf(r1.w);
        }
        __syncthreads();
        f32x4 o[4] = {};
        const ushort_t* vrow = row + 2048;
#pragma unroll
        for (int db = 0; db < 4; db++) {
            short8 bv = {};
            if (lane < 32) {
#pragma unroll
                for (int j = 0; j < 8; j++)
                    bv[j] = (short)vrow[(fo + j) * 64 + db * 16 + fr];
            }
            o[db] = __builtin_amdgcn_mfma_f32_16x16x32_bf16(pa, bv, o[db], 0, 0, 0);
        }
        float inv[4];
#pragma unroll
        for (int q = 0; q < 4; q++) inv[q] = 1.0f / sm[q];
        int b = tok >> 12;
        int n = tok & 4095;
        ushort_t* obase = operm + ((size_t)b << 22);
        int rlo = n >> 4;
        int cbase = (n & 15) * 64;
#pragma unroll
        for (int db = 0; db < 4; db++) {
#pragma unroll
            for (int q = 0; q < 4; q++) {
                int h = (lane >> 4) * 4 + q;
                int d = db * 16 + fr;
                obase[(size_t)(h * 256 + rlo) * 1024 + cbase + d] = f2bf(o[db][q] * inv[q]);
            }
        }
    }
}

extern "C" void kernel_launch(void* const* d_in, const int* in_sizes, int n_in,
                              void* d_out, int out_size, void* d_ws, size_t ws_size,
                              hipStream_t stream) {
    const float* x = (const float*)d_in[0];
    const float* w_qkv = (const float*)d_in[1];
    const float* w_proj = (const float*)d_in[2];
    const float* b_proj = (const float*)d_in[3];
    float* out = (float*)d_out;

    char* ws = (char*)d_ws;
    ushort_t* x_bf  = (ushort_t*)(ws);                  //  64 MiB: [32768][1024]
    ushort_t* wq_t  = (ushort_t*)(ws + 67108864);       //   6 MiB: [3072][1024]
    ushort_t* wp_t  = (ushort_t*)(ws + 73400320);       //   2 MiB: [1024][1024]
    ushort_t* qkv   = (ushort_t*)(ws + 75497472);       // 192 MiB: [32768][3072]
    ushort_t* operm = (ushort_t*)(ws + 276824064);      //  64 MiB: [32768][1024]

    cast_x_kernel<<<2048, 256, 0, stream>>>(x, x_bf, 33554432 / 8);
    transpose_cast_kernel<<<dim3(48, 16), 256, 0, stream>>>(w_qkv, wq_t, 1024, 3072);
    transpose_cast_kernel<<<dim3(16, 16), 256, 0, stream>>>(w_proj, wp_t, 1024, 1024);
    gemm256<0><<<1536, 512, 0, stream>>>(x_bf, wq_t, qkv, nullptr, 3072, 1024, 12);
    attn_kernel<<<2048, 256, 0, stream>>>(qkv, operm);
    gemm256<1><<<512, 512, 0, stream>>>(operm, wp_t, out, b_proj, 1024, 1024, 4);
}

// Round 4
// 397.600 us; speedup vs baseline: 1.2764x; 1.0039x over previous
//
#include <hip/hip_runtime.h>
#include <hip/hip_bf16.h>
#include <stdint.h>

typedef __attribute__((ext_vector_type(8))) short short8;
typedef __attribute__((ext_vector_type(4))) float f32x4;
typedef unsigned short ushort_t;

#define VMCNT4 asm volatile("s_waitcnt vmcnt(4)" ::: "memory")
#define VMCNT0 asm volatile("s_waitcnt vmcnt(0)" ::: "memory")
#define LGKM0  asm volatile("s_waitcnt lgkmcnt(0)" ::: "memory")
#define BARRIER asm volatile("s_barrier" ::: "memory")

__device__ inline ushort_t f2bf(float f) {
    union { float f; unsigned u; } v; v.f = f;
    unsigned u = v.u;
    unsigned r = u + 0x7fffu + ((u >> 16) & 1u);
    return (ushort_t)(r >> 16);
}

__device__ inline void gload_lds16(const void* g, void* l) {
    __builtin_amdgcn_global_load_lds((const __attribute__((address_space(1))) void*)g,
                                     (__attribute__((address_space(3))) void*)l,
                                     16, 0, 0);
}

// swizzled LDS frag read: region = 128x64 bf16 row-major (128B rows).
// Guideline-4 swizzle: XOR low 3 row bits into the 16B-slot index (byte bits 4-6).
__device__ inline short8 read_frag(const ushort_t* region, int r, int c) {
    int byte = (r << 7) + (c << 1);
    byte ^= (r & 7) << 4;
    return *(const short8*)((const char*)region + byte);
}

#define MFMA16(MB, NB, BF)                                                        \
    _Pragma("unroll")                                                             \
    for (int mi = 0; mi < 4; ++mi)                                                \
        _Pragma("unroll")                                                         \
        for (int ni = 0; ni < 2; ++ni)                                            \
            _Pragma("unroll")                                                     \
            for (int ks = 0; ks < 2; ++ks)                                        \
                acc[(MB) + mi][(NB) + ni] = __builtin_amdgcn_mfma_f32_16x16x32_bf16( \
                    aF[mi * 2 + ks], BF[ni * 2 + ks], acc[(MB) + mi][(NB) + ni], 0, 0, 0);

// ---------------- 256x256 8-phase GEMM: C[M][N] = A[M][K] * Bt[N][K]^T ----------------
// 8 waves (2M x 4N), BK=64, 128 KiB LDS, row&7 XOR swizzle.
// 4 barriers/tile (liveness-proven): post-MFMA barriers removed.
//  - A-stages issue with ds_reads (A other-slot dead since it-1; tile-end barrier syncs)
//  - B-stages issue after p3's pre-barrier (all-arrive => all waves' p2 lgkm0 done
//    => all B-slot-s reads complete => WAR-safe)
//  - vmcnt(4) before tile-end barrier => A(it+1)/B(it+1) landed for all waves
template <int F32OUT>
__global__ __launch_bounds__(512, 2) void gemm256(const ushort_t* __restrict__ A,
                                                  const ushort_t* __restrict__ Bt,
                                                  void* __restrict__ Cc,
                                                  const float* __restrict__ bias,
                                                  int N, int K, int NBN) {
    __shared__ __align__(16) ushort_t lds[65536];  // 128 KiB
    const int tid = threadIdx.x;
    const int wave = tid >> 6;
    const int lane = tid & 63;
    const int wm = wave >> 2;   // 0..1
    const int wn = wave & 3;    // 0..3
    // pre-swizzled source lane: linear LDS slot = lane&7, row-within-stripe = lane>>3
    const int el = (lane & 56) | ((lane ^ (lane >> 3)) & 7);

    // XCD-bijective swizzle (nwg%8==0) + 8-row supertile rasterization
    const int nwg = gridDim.x;
    const int bid = (int)blockIdx.x;
    const int x = (bid & 7) * (nwg >> 3) + (bid >> 3);
    const int per = NBN << 3;
    const int st = x / per;
    const int rem = x - st * per;
    const int bn = rem >> 3;
    const int bm = (st << 3) + (rem & 7);

    const ushort_t* Ag = A + (size_t)bm * 256 * K;
    const ushort_t* Bg = Bt + (size_t)bn * 256 * K;
    const int NT = K >> 6;

    auto STAGE = [&](const ushort_t* g, int rowHalf, int k0, int regionByteOff) {
#pragma unroll
        for (int j = 0; j < 2; ++j) {
            int e = j * 4096 + wave * 512 + el * 8;  // element within 128x64 half
            gload_lds16(g + (size_t)(rowHalf + (e >> 6)) * K + k0 + (e & 63),
                        (char*)lds + regionByteOff + j * 8192 + wave * 1024);
        }
    };

    // regions (bytes): A(slot,h) = (slot*2+h)*16384 ; B(slot,h) = 65536 + (slot*2+h)*16384
    // prologue: tile0 -> slot0 (all 4 halves), tile1 B-halves -> slot1
    STAGE(Ag, 0,   0, 0);
    STAGE(Ag, 128, 0, 16384);
    STAGE(Bg, 0,   0, 65536);
    STAGE(Bg, 128, 0, 65536 + 16384);
    STAGE(Bg, 0,   64, 65536 + 32768);
    STAGE(Bg, 128, 64, 65536 + 49152);
    VMCNT4;   // tile0 complete; tile1 B-halves stay in flight
    BARRIER;

    f32x4 acc[8][4] = {};
    short8 aF[8], bF0[4], bF1[4];
    const int ra = lane & 15;
    const int ca = (lane >> 4) << 3;
    const int rb = (wn & 1) << 6;

    for (int it = 0; it < NT; ++it) {
        const int s = it & 1;
        const ushort_t* Ar = lds + ((s << 1) + wm) * 8192;
        const ushort_t* Br = lds + 32768 + ((s << 1) + (wn >> 1)) * 8192;
        const bool doA = (it + 1) < NT;
        const bool doB = (it + 2) < NT;
        const int kA = (it + 1) << 6;
        const int kB = (it + 2) << 6;
        const int soA = ((s ^ 1) << 1) * 16384;        // other-slot A base
        const int soB = 65536 + (s << 1) * 16384;      // own-slot B base

        // ---- phase 1: reads aF-h0 + bF0 ; stage A0(it+1) early (region dead)
#pragma unroll
        for (int mi = 0; mi < 4; ++mi)
#pragma unroll
            for (int ks = 0; ks < 2; ++ks)
                aF[mi * 2 + ks] = read_frag(Ar, mi * 16 + ra, ks * 32 + ca);
#pragma unroll
        for (int ni = 0; ni < 2; ++ni)
#pragma unroll
            for (int ks = 0; ks < 2; ++ks)
                bF0[ni * 2 + ks] = read_frag(Br, rb + ni * 16 + ra, ks * 32 + ca);
        if (doA) STAGE(Ag, 0, kA, soA);
        BARRIER; LGKM0;
        __builtin_amdgcn_s_setprio(1);
        MFMA16(0, 0, bF0)
        __builtin_amdgcn_s_setprio(0);

        // ---- phase 2: reads bF1 ; stage A1(it+1)
#pragma unroll
        for (int ni = 0; ni < 2; ++ni)
#pragma unroll
            for (int ks = 0; ks < 2; ++ks)
                bF1[ni * 2 + ks] = read_frag(Br, rb + 32 + ni * 16 + ra, ks * 32 + ca);
        if (doA) STAGE(Ag, 128, kA, soA + 16384);
        BARRIER; LGKM0;
        __builtin_amdgcn_s_setprio(1);
        MFMA16(0, 2, bF1)
        __builtin_amdgcn_s_setprio(0);

        // ---- phase 3: reads aF-h1 ; barrier ; THEN stage B0(it+2) (WAR-safe)
#pragma unroll
        for (int mi = 0; mi < 4; ++mi)
#pragma unroll
            for (int ks = 0; ks < 2; ++ks)
                aF[mi * 2 + ks] = read_frag(Ar, 64 + mi * 16 + ra, ks * 32 + ca);
        BARRIER; LGKM0;
        if (doB) STAGE(Bg, 0, kB, soB);
        __builtin_amdgcn_s_setprio(1);
        MFMA16(4, 0, bF0)
        __builtin_amdgcn_s_setprio(0);

        // ---- phase 4: stage B1(it+2) ; MFMA ; vmcnt checkpoint ; tile-end barrier
        if (doB) STAGE(Bg, 128, kB, soB + 16384);
        __builtin_amdgcn_s_setprio(1);
        MFMA16(4, 2, bF1)
        __builtin_amdgcn_s_setprio(0);
        if (doB) { VMCNT4; } else { VMCNT0; }
        BARRIER;
    }

    // epilogue
    const int row0 = bm * 256 + wm * 128 + (lane >> 4) * 4;
    const int col0 = bn * 256 + wn * 64 + (lane & 15);
#pragma unroll
    for (int mi = 0; mi < 8; ++mi) {
#pragma unroll
        for (int ni = 0; ni < 4; ++ni) {
            const int col = col0 + ni * 16;
            f32x4 v = acc[mi][ni];
            if constexpr (F32OUT) {
                float bz = bias[col];
                float* C = (float*)Cc;
#pragma unroll
                for (int q = 0; q < 4; ++q)
                    C[(size_t)(row0 + mi * 16 + q) * N + col] = v[q] + bz;
            } else {
                ushort_t* C = (ushort_t*)Cc;
#pragma unroll
                for (int q = 0; q < 4; ++q)
                    C[(size_t)(row0 + mi * 16 + q) * N + col] = f2bf(v[q]);
            }
        }
    }
}

// ---------------- cast x f32 -> bf16, 8 elems/thread ----------------
__global__ __launch_bounds__(256) void cast_x_kernel(const float* __restrict__ in,
                                                     ushort_t* __restrict__ out,
                                                     int n8) {
    int i = blockIdx.x * blockDim.x + threadIdx.x;
    int stride = gridDim.x * blockDim.x;
    for (; i < n8; i += stride) {
        const float4* p = (const float4*)(in + (size_t)i * 8);
        float4 a = p[0];
        float4 b = p[1];
        uint4 w;
        w.x = (unsigned)f2bf(a.x) | ((unsigned)f2bf(a.y) << 16);
        w.y = (unsigned)f2bf(a.z) | ((unsigned)f2bf(a.w) << 16);
        w.z = (unsigned)f2bf(b.x) | ((unsigned)f2bf(b.y) << 16);
        w.w = (unsigned)f2bf(b.z) | ((unsigned)f2bf(b.w) << 16);
        *(uint4*)(out + (size_t)i * 8) = w;
    }
}

// ---------------- cast+transpose: in[R][Cn] f32 -> out[Cn][R] bf16 ----------------
__global__ __launch_bounds__(256) void transpose_cast_kernel(const float* __restrict__ in,
                                                             ushort_t* __restrict__ out,
                                                             int R, int Cn) {
    __shared__ float tile[64][65];
    int t = threadIdx.x;
    int c0 = blockIdx.x * 64;
    int r0 = blockIdx.y * 64;
    int lr = t >> 4;
    int lc = (t & 15) * 4;
#pragma unroll
    for (int i = 0; i < 4; i++) {
        const float* src = in + (size_t)(r0 + i * 16 + lr) * Cn + c0 + lc;
        float4 v = *(const float4*)src;
        tile[i * 16 + lr][lc + 0] = v.x;
        tile[i * 16 + lr][lc + 1] = v.y;
        tile[i * 16 + lr][lc + 2] = v.z;
        tile[i * 16 + lr][lc + 3] = v.w;
    }
    __syncthreads();
    int oc = t >> 4;
    int ok = (t & 15) * 4;
#pragma unroll
    for (int i = 0; i < 4; i++) {
        int c = c0 + i * 16 + oc;
        ushort4 w;
        w.x = f2bf(tile[ok + 0][i * 16 + oc]);
        w.y = f2bf(tile[ok + 1][i * 16 + oc]);
        w.z = f2bf(tile[ok + 2][i * 16 + oc]);
        w.w = f2bf(tile[ok + 3][i * 16 + oc]);
        *(ushort4*)(out + (size_t)c * R + r0 + ok) = w;
    }
}

// ---------------- per-token head-mixing attention ----------------
__global__ __launch_bounds__(256) void attn_kernel(const ushort_t* __restrict__ qkv,
                                                   ushort_t* __restrict__ operm) {
    __shared__ __align__(16) float plds[4][16 * 20];
    const int wave = threadIdx.x >> 6;
    const int lane = threadIdx.x & 63;
    float* P = plds[wave];
    const int fr = lane & 15;
    const int fo = (lane >> 4) * 8;
    int tok = (blockIdx.x * 4 + wave) * 4;
    for (int it = 0; it < 4; it++, tok++) {
        const ushort_t* row = qkv + (size_t)tok * 3072;
        short8 aq0 = *(const short8*)(row + fr * 64 + fo);
        short8 aq1 = *(const short8*)(row + fr * 64 + 32 + fo);
        short8 bk0 = *(const short8*)(row + 1024 + fr * 64 + fo);
        short8 bk1 = *(const short8*)(row + 1024 + fr * 64 + 32 + fo);
        f32x4 s = {0.f, 0.f, 0.f, 0.f};
        s = __builtin_amdgcn_mfma_f32_16x16x32_bf16(aq0, bk0, s, 0, 0, 0);
        s = __builtin_amdgcn_mfma_f32_16x16x32_bf16(aq1, bk1, s, 0, 0, 0);
        float ls[4], m[4], p[4], sm[4];
#pragma unroll
        for (int q = 0; q < 4; q++) { ls[q] = s[q] * 0.125f; m[q] = ls[q]; }
#pragma unroll
        for (int d = 1; d < 16; d <<= 1)
#pragma unroll
            for (int q = 0; q < 4; q++) m[q] = fmaxf(m[q], __shfl_xor(m[q], d));
#pragma unroll
        for (int q = 0; q < 4; q++) { p[q] = __expf(ls[q] - m[q]); sm[q] = p[q]; }
#pragma unroll
        for (int d = 1; d < 16; d <<= 1)
#pragma unroll
            for (int q = 0; q < 4; q++) sm[q] += __shfl_xor(sm[q], d);
#pragma unroll
        for (int q = 0; q < 4; q++) P[((lane >> 4) * 4 + q) * 20 + fr] = p[q];
        __syncthreads();
        short8 pa = {};
        if (lane < 32) {
            const float* src = P + fr * 20 + fo;
            float4 r0 = *(const float4*)src;
            float4 r1 = *(const float4*)(src + 4);
            pa[0] = (short)f2bf(r0.x); pa[1] = (short)f2bf(r0.y);
            pa[2] = (short)f2bf(r0.z); pa[3] = (short)f2bf(r0.w);
            pa[4] = (short)f2bf(r1.x); pa[5] = (short)f2bf(r1.y);
            pa[6] = (short)f2bf(r1.z); pa[7] = (short)f2bf(r1.w);
        }
        __syncthreads();
        f32x4 o[4] = {};
        const ushort_t* vrow = row + 2048;
#pragma unroll
        for (int db = 0; db < 4; db++) {
            short8 bv = {};
            if (lane < 32) {
#pragma unroll
                for (int j = 0; j < 8; j++)
                    bv[j] = (short)vrow[(fo + j) * 64 + db * 16 + fr];
            }
            o[db] = __builtin_amdgcn_mfma_f32_16x16x32_bf16(pa, bv, o[db], 0, 0, 0);
        }
        float inv[4];
#pragma unroll
        for (int q = 0; q < 4; q++) inv[q] = 1.0f / sm[q];
        int b = tok >> 12;
        int n = tok & 4095;
        ushort_t* obase = operm + ((size_t)b << 22);
        int rlo = n >> 4;
        int cbase = (n & 15) * 64;
#pragma unroll
        for (int db = 0; db < 4; db++) {
#pragma unroll
            for (int q = 0; q < 4; q++) {
                int h = (lane >> 4) * 4 + q;
                int d = db * 16 + fr;
                obase[(size_t)(h * 256 + rlo) * 1024 + cbase + d] = f2bf(o[db][q] * inv[q]);
            }
        }
    }
}

extern "C" void kernel_launch(void* const* d_in, const int* in_sizes, int n_in,
                              void* d_out, int out_size, void* d_ws, size_t ws_size,
                              hipStream_t stream) {
    const float* x = (const float*)d_in[0];
    const float* w_qkv = (const float*)d_in[1];
    const float* w_proj = (const float*)d_in[2];
    const float* b_proj = (const float*)d_in[3];
    float* out = (float*)d_out;

    char* ws = (char*)d_ws;
    ushort_t* x_bf  = (ushort_t*)(ws);                  //  64 MiB: [32768][1024]
    ushort_t* wq_t  = (ushort_t*)(ws + 67108864);       //   6 MiB: [3072][1024]
    ushort_t* wp_t  = (ushort_t*)(ws + 73400320);       //   2 MiB: [1024][1024]
    ushort_t* qkv   = (ushort_t*)(ws + 75497472);       // 192 MiB: [32768][3072]
    ushort_t* operm = (ushort_t*)(ws + 276824064);      //  64 MiB: [32768][1024]

    cast_x_kernel<<<2048, 256, 0, stream>>>(x, x_bf, 33554432 / 8);
    transpose_cast_kernel<<<dim3(48, 16), 256, 0, stream>>>(w_qkv, wq_t, 1024, 3072);
    transpose_cast_kernel<<<dim3(16, 16), 256, 0, stream>>>(w_proj, wp_t, 1024, 1024);
    gemm256<0><<<1536, 512, 0, stream>>>(x_bf, wq_t, qkv, nullptr, 3072, 1024, 12);
    attn_kernel<<<2048, 256, 0, stream>>>(qkv, operm);
    gemm256<1><<<512, 512, 0, stream>>>(operm, wp_t, out, b_proj, 1024, 1024, 4);
}

// Round 5
// 388.961 us; speedup vs baseline: 1.3048x; 1.0222x over previous
//
#include <hip/hip_runtime.h>
#include <hip/hip_bf16.h>
#include <stdint.h>

typedef __attribute__((ext_vector_type(8))) short short8;
typedef __attribute__((ext_vector_type(4))) float f32x4;
typedef unsigned short ushort_t;

#define VMCNT4 asm volatile("s_waitcnt vmcnt(4)" ::: "memory")
#define VMCNT0 asm volatile("s_waitcnt vmcnt(0)" ::: "memory")
#define LGKM0  asm volatile("s_waitcnt lgkmcnt(0)" ::: "memory")
#define BARRIER asm volatile("s_barrier" ::: "memory")

__device__ inline ushort_t f2bf(float f) {
    union { float f; unsigned u; } v; v.f = f;
    unsigned u = v.u;
    unsigned r = u + 0x7fffu + ((u >> 16) & 1u);
    return (ushort_t)(r >> 16);
}

__device__ inline void gload_lds16(const void* g, void* l) {
    __builtin_amdgcn_global_load_lds((const __attribute__((address_space(1))) void*)g,
                                     (__attribute__((address_space(3))) void*)l,
                                     16, 0, 0);
}

// swizzled LDS frag read: region = 128x64 bf16 row-major (128B rows).
// Guideline-4 swizzle: XOR low 3 row bits into the 16B-slot index (byte bits 4-6).
__device__ inline short8 read_frag(const ushort_t* region, int r, int c) {
    int byte = (r << 7) + (c << 1);
    byte ^= (r & 7) << 4;
    return *(const short8*)((const char*)region + byte);
}

#define MFMA16(MB, NB, BF)                                                        \
    _Pragma("unroll")                                                             \
    for (int mi = 0; mi < 4; ++mi)                                                \
        _Pragma("unroll")                                                         \
        for (int ni = 0; ni < 2; ++ni)                                            \
            _Pragma("unroll")                                                     \
            for (int ks = 0; ks < 2; ++ks)                                        \
                acc[(MB) + mi][(NB) + ni] = __builtin_amdgcn_mfma_f32_16x16x32_bf16( \
                    aF[mi * 2 + ks], BF[ni * 2 + ks], acc[(MB) + mi][(NB) + ni], 0, 0, 0);

// ---------------- persistent 256x256 8-phase GEMM: C[M][N] = A[M][K] * Bt[N][K]^T ----
// grid = 256 (1 block/CU); each block loops over LT/256 logical tiles.
// Cross-tile software pipeline: at tile end the staging pointers redirect to the
// next tile's panels (same slot invariant), so the K-stream never drains except
// at the very last tile. Epilogue stores overlap the next tile's first phases.
template <int F32OUT>
__global__ __launch_bounds__(512, 2) void gemm256(const ushort_t* __restrict__ A,
                                                  const ushort_t* __restrict__ Bt,
                                                  void* __restrict__ Cc,
                                                  const float* __restrict__ bias,
                                                  int N, int K, int NBN, int LT) {
    __shared__ __align__(16) ushort_t lds[65536];  // 128 KiB
    const int tid = threadIdx.x;
    const int wave = tid >> 6;
    const int lane = tid & 63;
    const int wm = wave >> 2;   // 0..1
    const int wn = wave & 3;    // 0..3
    // pre-swizzled source lane: linear LDS slot = lane&7, row-within-stripe = lane>>3
    const int el = (lane & 56) | ((lane ^ (lane >> 3)) & 7);
    const int NT = K >> 6;      // power of two (16 here)
    const int NTM = NT - 1;

    // XCD-bijective swizzle (LT%8==0) + 8-row supertile rasterization
    auto tile_of = [&](int lt, int& obm, int& obn) {
        int x = (lt & 7) * (LT >> 3) + (lt >> 3);
        int per = NBN << 3;
        int st = x / per;
        int rem = x - st * per;
        obn = rem >> 3;
        obm = (st << 3) + (rem & 7);
    };

    auto STAGE = [&](const ushort_t* g, int rowHalf, int k0, int regionByteOff) {
#pragma unroll
        for (int j = 0; j < 2; ++j) {
            int e = j * 4096 + wave * 512 + el * 8;  // element within 128x64 half
            gload_lds16(g + (size_t)(rowHalf + (e >> 6)) * K + k0 + (e & 63),
                        (char*)lds + regionByteOff + j * 8192 + wave * 1024);
        }
    };

    int bm, bn;
    tile_of((int)blockIdx.x, bm, bn);
    const ushort_t* Ag = A + (size_t)bm * 256 * K;
    const ushort_t* Bg = Bt + (size_t)bn * 256 * K;

    // regions (bytes): A(slot,h) = (slot*2+h)*16384 ; B(slot,h) = 65536 + (slot*2+h)*16384
    // prologue (once per kernel): tile0 K-tile0 (A+B) -> slot0, K-tile1 B -> slot1
    STAGE(Ag, 0,   0, 0);
    STAGE(Ag, 128, 0, 16384);
    STAGE(Bg, 0,   0, 65536);
    STAGE(Bg, 128, 0, 65536 + 16384);
    STAGE(Bg, 0,   64, 65536 + 32768);
    STAGE(Bg, 128, 64, 65536 + 49152);
    VMCNT4;
    BARRIER;

    f32x4 acc[8][4] = {};
    short8 aF[8], bF0[4], bF1[4];
    const f32x4 zf = {0.f, 0.f, 0.f, 0.f};
    const int ra = lane & 15;
    const int ca = (lane >> 4) << 3;
    const int rb = (wn & 1) << 6;

    for (int lt = (int)blockIdx.x; lt < LT; lt += 256) {
        const bool hasN = (lt + 256) < LT;
        int bmN = bm, bnN = bn;
        const ushort_t* AgN = Ag;
        const ushort_t* BgN = Bg;
        if (hasN) {
            tile_of(lt + 256, bmN, bnN);
            AgN = A + (size_t)bmN * 256 * K;
            BgN = Bt + (size_t)bnN * 256 * K;
        }

        for (int it = 0; it < NT; ++it) {
            const int s = it & 1;
            const ushort_t* Ar = lds + ((s << 1) + wm) * 8192;
            const ushort_t* Br = lds + 32768 + ((s << 1) + (wn >> 1)) * 8192;
            const int itA = it + 1, itB = it + 2;
            const bool doA = (itA < NT) || hasN;
            const bool doB = (itB < NT) || hasN;
            const ushort_t* As = (itA < NT) ? Ag : AgN;   // redirect across tile boundary
            const ushort_t* Bs = (itB < NT) ? Bg : BgN;
            const int kA = (itA & NTM) << 6;
            const int kB = (itB & NTM) << 6;
            const int soA = ((s ^ 1) << 1) * 16384;        // other-slot A base
            const int soB = 65536 + (s << 1) * 16384;      // own-slot B base

            // ---- phase 1: reads aF-h0 + bF0 ; stage A0(next) early (region dead)
#pragma unroll
            for (int mi = 0; mi < 4; ++mi)
#pragma unroll
                for (int ks = 0; ks < 2; ++ks)
                    aF[mi * 2 + ks] = read_frag(Ar, mi * 16 + ra, ks * 32 + ca);
#pragma unroll
            for (int ni = 0; ni < 2; ++ni)
#pragma unroll
                for (int ks = 0; ks < 2; ++ks)
                    bF0[ni * 2 + ks] = read_frag(Br, rb + ni * 16 + ra, ks * 32 + ca);
            if (doA) STAGE(As, 0, kA, soA);
            BARRIER; LGKM0;
            __builtin_amdgcn_s_setprio(1);
            MFMA16(0, 0, bF0)
            __builtin_amdgcn_s_setprio(0);

            // ---- phase 2: reads bF1 ; stage A1(next)
#pragma unroll
            for (int ni = 0; ni < 2; ++ni)
#pragma unroll
                for (int ks = 0; ks < 2; ++ks)
                    bF1[ni * 2 + ks] = read_frag(Br, rb + 32 + ni * 16 + ra, ks * 32 + ca);
            if (doA) STAGE(As, 128, kA, soA + 16384);
            BARRIER; LGKM0;
            __builtin_amdgcn_s_setprio(1);
            MFMA16(0, 2, bF1)
            __builtin_amdgcn_s_setprio(0);

            // ---- phase 3: reads aF-h1 ; barrier ; THEN stage B0(next+1) (WAR-safe)
#pragma unroll
            for (int mi = 0; mi < 4; ++mi)
#pragma unroll
                for (int ks = 0; ks < 2; ++ks)
                    aF[mi * 2 + ks] = read_frag(Ar, 64 + mi * 16 + ra, ks * 32 + ca);
            BARRIER; LGKM0;
            if (doB) STAGE(Bs, 0, kB, soB);
            __builtin_amdgcn_s_setprio(1);
            MFMA16(4, 0, bF0)
            __builtin_amdgcn_s_setprio(0);

            // ---- phase 4: stage B1(next+1) ; MFMA ; vmcnt checkpoint ; tile-end barrier
            if (doB) STAGE(Bs, 128, kB, soB + 16384);
            __builtin_amdgcn_s_setprio(1);
            MFMA16(4, 2, bF1)
            __builtin_amdgcn_s_setprio(0);
            if (doB) { VMCNT4; } else { VMCNT0; }
            BARRIER;
        }

        // ---- epilogue for (bm,bn): stores overlap next tile's first phases
        const int row0 = bm * 256 + wm * 128 + (lane >> 4) * 4;
        const int col0 = bn * 256 + wn * 64 + (lane & 15);
#pragma unroll
        for (int mi = 0; mi < 8; ++mi) {
#pragma unroll
            for (int ni = 0; ni < 4; ++ni) {
                const int col = col0 + ni * 16;
                f32x4 v = acc[mi][ni];
                if constexpr (F32OUT) {
                    float bz = bias[col];
                    float* C = (float*)Cc;
#pragma unroll
                    for (int q = 0; q < 4; ++q)
                        C[(size_t)(row0 + mi * 16 + q) * N + col] = v[q] + bz;
                } else {
                    ushort_t* C = (ushort_t*)Cc;
#pragma unroll
                    for (int q = 0; q < 4; ++q)
                        C[(size_t)(row0 + mi * 16 + q) * N + col] = f2bf(v[q]);
                }
                acc[mi][ni] = zf;
            }
        }
        Ag = AgN; Bg = BgN; bm = bmN; bn = bnN;
    }
}

// ---------------- cast x f32 -> bf16, 8 elems/thread ----------------
__global__ __launch_bounds__(256) void cast_x_kernel(const float* __restrict__ in,
                                                     ushort_t* __restrict__ out,
                                                     int n8) {
    int i = blockIdx.x * blockDim.x + threadIdx.x;
    int stride = gridDim.x * blockDim.x;
    for (; i < n8; i += stride) {
        const float4* p = (const float4*)(in + (size_t)i * 8);
        float4 a = p[0];
        float4 b = p[1];
        uint4 w;
        w.x = (unsigned)f2bf(a.x) | ((unsigned)f2bf(a.y) << 16);
        w.y = (unsigned)f2bf(a.z) | ((unsigned)f2bf(a.w) << 16);
        w.z = (unsigned)f2bf(b.x) | ((unsigned)f2bf(b.y) << 16);
        w.w = (unsigned)f2bf(b.z) | ((unsigned)f2bf(b.w) << 16);
        *(uint4*)(out + (size_t)i * 8) = w;
    }
}

// ---------------- cast+transpose: in[R][Cn] f32 -> out[Cn][R] bf16 ----------------
__global__ __launch_bounds__(256) void transpose_cast_kernel(const float* __restrict__ in,
                                                             ushort_t* __restrict__ out,
                                                             int R, int Cn) {
    __shared__ float tile[64][65];
    int t = threadIdx.x;
    int c0 = blockIdx.x * 64;
    int r0 = blockIdx.y * 64;
    int lr = t >> 4;
    int lc = (t & 15) * 4;
#pragma unroll
    for (int i = 0; i < 4; i++) {
        const float* src = in + (size_t)(r0 + i * 16 + lr) * Cn + c0 + lc;
        float4 v = *(const float4*)src;
        tile[i * 16 + lr][lc + 0] = v.x;
        tile[i * 16 + lr][lc + 1] = v.y;
        tile[i * 16 + lr][lc + 2] = v.z;
        tile[i * 16 + lr][lc + 3] = v.w;
    }
    __syncthreads();
    int oc = t >> 4;
    int ok = (t & 15) * 4;
#pragma unroll
    for (int i = 0; i < 4; i++) {
        int c = c0 + i * 16 + oc;
        ushort4 w;
        w.x = f2bf(tile[ok + 0][i * 16 + oc]);
        w.y = f2bf(tile[ok + 1][i * 16 + oc]);
        w.z = f2bf(tile[ok + 2][i * 16 + oc]);
        w.w = f2bf(tile[ok + 3][i * 16 + oc]);
        *(ushort4*)(out + (size_t)c * R + r0 + ok) = w;
    }
}

// ---------------- per-token head-mixing attention ----------------
__global__ __launch_bounds__(256) void attn_kernel(const ushort_t* __restrict__ qkv,
                                                   ushort_t* __restrict__ operm) {
    __shared__ __align__(16) float plds[4][16 * 20];
    const int wave = threadIdx.x >> 6;
    const int lane = threadIdx.x & 63;
    float* P = plds[wave];
    const int fr = lane & 15;
    const int fo = (lane >> 4) * 8;
    int tok = (blockIdx.x * 4 + wave) * 4;
    for (int it = 0; it < 4; it++, tok++) {
        const ushort_t* row = qkv + (size_t)tok * 3072;
        short8 aq0 = *(const short8*)(row + fr * 64 + fo);
        short8 aq1 = *(const short8*)(row + fr * 64 + 32 + fo);
        short8 bk0 = *(const short8*)(row + 1024 + fr * 64 + fo);
        short8 bk1 = *(const short8*)(row + 1024 + fr * 64 + 32 + fo);
        f32x4 s = {0.f, 0.f, 0.f, 0.f};
        s = __builtin_amdgcn_mfma_f32_16x16x32_bf16(aq0, bk0, s, 0, 0, 0);
        s = __builtin_amdgcn_mfma_f32_16x16x32_bf16(aq1, bk1, s, 0, 0, 0);
        float ls[4], m[4], p[4], sm[4];
#pragma unroll
        for (int q = 0; q < 4; q++) { ls[q] = s[q] * 0.125f; m[q] = ls[q]; }
#pragma unroll
        for (int d = 1; d < 16; d <<= 1)
#pragma unroll
            for (int q = 0; q < 4; q++) m[q] = fmaxf(m[q], __shfl_xor(m[q], d));
#pragma unroll
        for (int q = 0; q < 4; q++) { p[q] = __expf(ls[q] - m[q]); sm[q] = p[q]; }
#pragma unroll
        for (int d = 1; d < 16; d <<= 1)
#pragma unroll
            for (int q = 0; q < 4; q++) sm[q] += __shfl_xor(sm[q], d);
#pragma unroll
        for (int q = 0; q < 4; q++) P[((lane >> 4) * 4 + q) * 20 + fr] = p[q];
        __syncthreads();
        short8 pa = {};
        if (lane < 32) {
            const float* src = P + fr * 20 + fo;
            float4 r0 = *(const float4*)src;
            float4 r1 = *(const float4*)(src + 4);
            pa[0] = (short)f2bf(r0.x); pa[1] = (short)f2bf(r0.y);
            pa[2] = (short)f2bf(r0.z); pa[3] = (short)f2bf(r0.w);
            pa[4] = (short)f2bf(r1.x); pa[5] = (short)f2bf(r1.y);
            pa[6] = (short)f2bf(r1.z); pa[7] = (short)f2bf(r1.w);
        }
        __syncthreads();
        f32x4 o[4] = {};
        const ushort_t* vrow = row + 2048;
#pragma unroll
        for (int db = 0; db < 4; db++) {
            short8 bv = {};
            if (lane < 32) {
#pragma unroll
                for (int j = 0; j < 8; j++)
                    bv[j] = (short)vrow[(fo + j) * 64 + db * 16 + fr];
            }
            o[db] = __builtin_amdgcn_mfma_f32_16x16x32_bf16(pa, bv, o[db], 0, 0, 0);
        }
        float inv[4];
#pragma unroll
        for (int q = 0; q < 4; q++) inv[q] = 1.0f / sm[q];
        int b = tok >> 12;
        int n = tok & 4095;
        ushort_t* obase = operm + ((size_t)b << 22);
        int rlo = n >> 4;
        int cbase = (n & 15) * 64;
#pragma unroll
        for (int db = 0; db < 4; db++) {
#pragma unroll
            for (int q = 0; q < 4; q++) {
                int h = (lane >> 4) * 4 + q;
                int d = db * 16 + fr;
                obase[(size_t)(h * 256 + rlo) * 1024 + cbase + d] = f2bf(o[db][q] * inv[q]);
            }
        }
    }
}

extern "C" void kernel_launch(void* const* d_in, const int* in_sizes, int n_in,
                              void* d_out, int out_size, void* d_ws, size_t ws_size,
                              hipStream_t stream) {
    const float* x = (const float*)d_in[0];
    const float* w_qkv = (const float*)d_in[1];
    const float* w_proj = (const float*)d_in[2];
    const float* b_proj = (const float*)d_in[3];
    float* out = (float*)d_out;

    char* ws = (char*)d_ws;
    ushort_t* x_bf  = (ushort_t*)(ws);                  //  64 MiB: [32768][1024]
    ushort_t* wq_t  = (ushort_t*)(ws + 67108864);       //   6 MiB: [3072][1024]
    ushort_t* wp_t  = (ushort_t*)(ws + 73400320);       //   2 MiB: [1024][1024]
    ushort_t* qkv   = (ushort_t*)(ws + 75497472);       // 192 MiB: [32768][3072]
    ushort_t* operm = (ushort_t*)(ws + 276824064);      //  64 MiB: [32768][1024]

    cast_x_kernel<<<2048, 256, 0, stream>>>(x, x_bf, 33554432 / 8);
    transpose_cast_kernel<<<dim3(48, 16), 256, 0, stream>>>(w_qkv, wq_t, 1024, 3072);
    transpose_cast_kernel<<<dim3(16, 16), 256, 0, stream>>>(w_proj, wp_t, 1024, 1024);
    gemm256<0><<<256, 512, 0, stream>>>(x_bf, wq_t, qkv, nullptr, 3072, 1024, 12, 1536);
    attn_kernel<<<2048, 256, 0, stream>>>(qkv, operm);
    gemm256<1><<<256, 512, 0, stream>>>(operm, wp_t, out, b_proj, 1024, 1024, 4, 512);
}